// Round 1
// baseline (29787.985 us; speedup 1.0000x reference)
//
#include <hip/hip_runtime.h>
#include <hip/hip_bf16.h>
#include <math.h>

namespace {

constexpr int NU   = 50000;
constexpr int NI   = 30000;
constexpr int D    = 128;
constexpr int EUG  = 2000000;
constexpr int EAND = 1000000;
constexpr int EOR  = 1000000;

struct AttnArgs {
  const float* layer[7];
  float coef[7];
};

__global__ void deg_count_k(const int* __restrict__ idx, int E, float* __restrict__ deg) {
  int t = blockIdx.x * 256 + threadIdx.x;
  if (t < E) unsafeAtomicAdd(&deg[idx[t]], 1.0f);
}

__global__ void inv_sqrt_k(float* __restrict__ d, int n) {
  int t = blockIdx.x * 256 + threadIdx.x;
  if (t < n) d[t] = 1.0f / sqrtf(fmaxf(d[t], 1.0f));
}

// 32 threads per edge, each handles 4 contiguous floats (float4 gather, 4 atomics scatter)
__global__ void gcn_scatter_k(const float* __restrict__ x, const int* __restrict__ src,
                              const int* __restrict__ dst, const float* __restrict__ inv_out,
                              const float* __restrict__ ew, const float* __restrict__ nw,
                              float* __restrict__ agg, int E) {
  int t = blockIdx.x * 256 + threadIdx.x;
  int e = t >> 5;
  if (e >= E) return;
  int lane = t & 31;
  int s = src[e];
  int d = dst[e];
  float sc = inv_out[s];
  if (ew) sc *= ew[e];
  if (nw) sc *= nw[s];
  float4 v = ((const float4*)(x + (size_t)s * D))[lane];
  float* o = agg + (size_t)d * D + (lane << 2);
  unsafeAtomicAdd(o + 0, v.x * sc);
  unsafeAtomicAdd(o + 1, v.y * sc);
  unsafeAtomicAdd(o + 2, v.z * sc);
  unsafeAtomicAdd(o + 3, v.w * sc);
}

__global__ void scale_rows_k(float* __restrict__ x, const float* __restrict__ inv_in, long n4) {
  long t = (long)blockIdx.x * 256 + threadIdx.x;
  if (t < n4) {
    int row = (int)(t >> 5);
    float s = inv_in[row];
    float4 v = ((float4*)x)[t];
    v.x *= s; v.y *= s; v.z *= s; v.w *= s;
    ((float4*)x)[t] = v;
  }
}

__device__ inline void osm_upd(float& m, float& den, float& num, float sc, float tv) {
  float nm = fmaxf(m, sc);
  float e0 = __expf(m - nm);
  float e1 = __expf(sc - nm);
  den = den * e0 + e1;
  num = num * e0 + tv * e1;
  m = nm;
}

// Per-channel layer attention, online softmax over L layers.
// Block = 256 threads = 8 nodes x 32 d-groups (4 channels each).
template <int L>
__global__ __launch_bounds__(256) void attn_k(AttnArgs args,
    const float* __restrict__ W, const float* __restrict__ avec,
    float* __restrict__ out, float out_scale, int beta, int n) {
  __shared__ float xs[8][D];
  const int nt = threadIdx.x >> 5;
  const int dt = threadIdx.x & 31;
  const float4 a4 = ((const float4*)avec)[dt];
  const float4* __restrict__ W4 = (const float4*)W;

  int node = blockIdx.x * 8 + nt;
  float m[4], den[4], num[4];
#pragma unroll
  for (int j = 0; j < 4; ++j) { m[j] = -3.0e38f; den[j] = 0.f; num[j] = 0.f; }

#pragma unroll
  for (int l = 0; l < L; ++l) {
    __syncthreads();
    if (node < n)
      ((float4*)xs[nt])[dt] = ((const float4*)(args.layer[l] + (size_t)node * D))[dt];
    __syncthreads();
    if (node < n) {
      float s0 = 0.f, s1 = 0.f, s2 = 0.f, s3 = 0.f;
#pragma unroll 8
      for (int k = 0; k < D; ++k) {
        float xv = xs[nt][k];
        float4 w = W4[k * 32 + dt];
        s0 = fmaf(xv, w.x, s0);
        s1 = fmaf(xv, w.y, s1);
        s2 = fmaf(xv, w.z, s2);
        s3 = fmaf(xv, w.w, s3);
      }
      float c = args.coef[l];
      float4 tv = ((float4*)xs[nt])[dt];
      osm_upd(m[0], den[0], num[0], c * s0 * a4.x, c * tv.x);
      osm_upd(m[1], den[1], num[1], c * s1 * a4.y, c * tv.y);
      osm_upd(m[2], den[2], num[2], c * s2 * a4.z, c * tv.z);
      osm_upd(m[3], den[3], num[3], c * s3 * a4.w, c * tv.w);
    }
  }
  if (node < n) {
    float4 o;
    o.x = num[0] / den[0];
    o.y = num[1] / den[1];
    o.z = num[2] / den[2];
    o.w = num[3] / den[3];
    float4* op = ((float4*)(out + (size_t)node * D)) + dt;
    if (beta) {
      float4 pv = *op;
      o.x = pv.x + out_scale * o.x;
      o.y = pv.y + out_scale * o.y;
      o.z = pv.z + out_scale * o.z;
      o.w = pv.w + out_scale * o.w;
    } else {
      o.x *= out_scale; o.y *= out_scale; o.z *= out_scale; o.w *= out_scale;
    }
    *op = o;
  }
}

__global__ void copy4_k(float* __restrict__ dst, const float* __restrict__ src, long n4) {
  long t = (long)blockIdx.x * 256 + threadIdx.x;
  if (t < n4) ((float4*)dst)[t] = ((const float4*)src)[t];
}

__global__ void axpy4_k(float* __restrict__ dst, const float* __restrict__ src, float a, long n4) {
  long t = (long)blockIdx.x * 256 + threadIdx.x;
  if (t < n4) {
    float4 v = ((const float4*)src)[t];
    float4 o = ((float4*)dst)[t];
    o.x += a * v.x; o.y += a * v.y; o.z += a * v.z; o.w += a * v.w;
    ((float4*)dst)[t] = o;
  }
}

inline dim3 g1(long n) { return dim3((unsigned)((n + 255) / 256)); }

} // namespace

extern "C" void kernel_launch(void* const* d_in, const int* in_sizes, int n_in,
                              void* d_out, int out_size, void* d_ws, size_t ws_size,
                              hipStream_t stream) {
  const int* ug_u = (const int*)d_in[0];
  const int* ug_g = (const int*)d_in[1];
  const int* aS[3] = {(const int*)d_in[2], (const int*)d_in[4], (const int*)d_in[6]};
  const int* aD[3] = {(const int*)d_in[3], (const int*)d_in[5], (const int*)d_in[7]};
  const int* oS = (const int*)d_in[8];
  const int* oD = (const int*)d_in[9];
  const float* ue    = (const float*)d_in[10];
  const float* ie    = (const float*)d_in[11];
  const float* W_and = (const float*)d_in[12];
  const float* a_and = (const float*)d_in[13];
  const float* W_or  = (const float*)d_in[14];
  const float* a_or  = (const float*)d_in[15];
  const float* wedge = (const float*)d_in[16];
  const float* wnode = (const float*)d_in[17];

  // workspace layout (all float, 16B-aligned chunks)
  float* p = (float*)d_ws;
  float* invU = p; p += NU;
  float* invG = p; p += NI;
  float* iAo[3]; float* iAi[3];
  for (int i = 0; i < 3; ++i) { iAo[i] = p; p += NI; iAi[i] = p; p += NI; }
  float* iOo = p; p += NI;
  float* iOi = p; p += NI;
  float* hu1 = p; p += (size_t)NU * D;
  float* hu2 = p; p += (size_t)NU * D;
  float* hg1 = p; p += (size_t)NI * D;
  float* hg2 = p; p += (size_t)NI * D;
  float* ab[6]; for (int i = 0; i < 6; ++i) { ab[i] = p; p += (size_t)NI * D; }
  float* ob[3]; for (int i = 0; i < 3; ++i) { ob[i] = p; p += (size_t)NI * D; }
  size_t total_bytes = (size_t)((char*)p - (char*)d_ws);

  hipMemsetAsync(d_ws, 0, total_bytes, stream);

  // ---- degree histograms -> rsqrt norms ----
  deg_count_k<<<g1(EUG), 256, 0, stream>>>(ug_u, EUG, invU);
  deg_count_k<<<g1(EUG), 256, 0, stream>>>(ug_g, EUG, invG);
  for (int i = 0; i < 3; ++i) {
    deg_count_k<<<g1(EAND), 256, 0, stream>>>(aS[i], EAND, iAo[i]);
    deg_count_k<<<g1(EAND), 256, 0, stream>>>(aD[i], EAND, iAi[i]);
  }
  deg_count_k<<<g1(EOR), 256, 0, stream>>>(oS, EOR, iOo);
  deg_count_k<<<g1(EOR), 256, 0, stream>>>(oD, EOR, iOi);
  int normsN = NU + 9 * NI;
  inv_sqrt_k<<<g1(normsN), 256, 0, stream>>>(invU, normsN);

  // ---- user-game propagation, 2 layers ----
  gcn_scatter_k<<<g1((long)EUG * 32), 256, 0, stream>>>(ie, ug_g, ug_u, invG, wedge, wnode, hu1, EUG);
  gcn_scatter_k<<<g1((long)EUG * 32), 256, 0, stream>>>(ue, ug_u, ug_g, invU, nullptr, nullptr, hg1, EUG);
  scale_rows_k<<<g1((long)NU * 32), 256, 0, stream>>>(hu1, invU, (long)NU * 32);
  scale_rows_k<<<g1((long)NI * 32), 256, 0, stream>>>(hg1, invG, (long)NI * 32);

  gcn_scatter_k<<<g1((long)EUG * 32), 256, 0, stream>>>(hg1, ug_g, ug_u, invG, wedge, wnode, hu2, EUG);
  gcn_scatter_k<<<g1((long)EUG * 32), 256, 0, stream>>>(hu1, ug_u, ug_g, invU, nullptr, nullptr, hg2, EUG);
  scale_rows_k<<<g1((long)NU * 32), 256, 0, stream>>>(hu2, invU, (long)NU * 32);
  scale_rows_k<<<g1((long)NI * 32), 256, 0, stream>>>(hg2, invG, (long)NI * 32);

  // ---- AND chains: 3 graphs x 2 layers ----
  for (int i = 0; i < 3; ++i) {
    gcn_scatter_k<<<g1((long)EAND * 32), 256, 0, stream>>>(ie, aS[i], aD[i], iAo[i], nullptr, nullptr, ab[i], EAND);
    scale_rows_k<<<g1((long)NI * 32), 256, 0, stream>>>(ab[i], iAi[i], (long)NI * 32);
  }
  for (int i = 0; i < 3; ++i) {
    gcn_scatter_k<<<g1((long)EAND * 32), 256, 0, stream>>>(ab[i], aS[i], aD[i], iAo[i], nullptr, nullptr, ab[3 + i], EAND);
    scale_rows_k<<<g1((long)NI * 32), 256, 0, stream>>>(ab[3 + i], iAi[i], (long)NI * 32);
  }

  // ---- OR chain: 3 layers ----
  {
    const float* srcp = ie;
    for (int i = 0; i < 3; ++i) {
      gcn_scatter_k<<<g1((long)EOR * 32), 256, 0, stream>>>(srcp, oS, oD, iOo, nullptr, nullptr, ob[i], EOR);
      scale_rows_k<<<g1((long)NI * 32), 256, 0, stream>>>(ob[i], iOi, (long)NI * 32);
      srcp = ob[i];
    }
  }

  float* out_hu = (float*)d_out;
  float* out_game = out_hu + (size_t)NU * D;

  const float w_or = 80.0f / 82.0f;
  const float w_and = w_or / 80.0f;   // = 1/82
  const float w_self = w_and;

  // ---- layer attention (AND: 7 layers, OR: 4 layers with decay coefs) ----
  AttnArgs aa{};
  aa.layer[0] = ie;
  for (int i = 0; i < 6; ++i) aa.layer[1 + i] = ab[i];
  for (int i = 0; i < 7; ++i) aa.coef[i] = 1.0f;
  attn_k<7><<<dim3((NI + 7) / 8), 256, 0, stream>>>(aa, W_and, a_and, out_game, w_and, 0, NI);

  AttnArgs ao{};
  ao.layer[0] = ie; ao.layer[1] = ob[0]; ao.layer[2] = ob[1]; ao.layer[3] = ob[2];
  ao.coef[0] = 1.0f; ao.coef[1] = 0.6f; ao.coef[2] = 0.8f; ao.coef[3] = 1.0f;
  attn_k<4><<<dim3((NI + 7) / 8), 256, 0, stream>>>(ao, W_or, a_or, out_game, w_or, 1, NI);

  // ---- combine: out_game += w_self * hg2 ; out_hu = hu2 ----
  axpy4_k<<<g1((long)NI * 32), 256, 0, stream>>>(out_game, hg2, w_self, (long)NI * 32);
  copy4_k<<<g1((long)NU * 32), 256, 0, stream>>>(out_hu, hu2, (long)NU * 32);
}

// Round 2
// 3204.897 us; speedup vs baseline: 9.2945x; 9.2945x over previous
//
#include <hip/hip_runtime.h>
#include <hip/hip_bf16.h>
#include <math.h>

namespace {

constexpr int NU   = 50000;
constexpr int NI   = 30000;
constexpr int D    = 128;
constexpr int EUG  = 2000000;
constexpr int EAND = 1000000;
constexpr int EOR  = 1000000;

struct AttnArgs {
  const float* layer[7];
  float coef[7];
};

// ---------- CSR build ----------

__global__ void count_k(const int* __restrict__ idx, int E, int* __restrict__ cnt) {
  int t = blockIdx.x * 256 + threadIdx.x;
  if (t < E) atomicAdd(&cnt[idx[t]], 1);
}

__global__ void norms_k(const int* __restrict__ cnt, float* __restrict__ inv, int n) {
  int t = blockIdx.x * 256 + threadIdx.x;
  if (t < n) inv[t] = rsqrtf((float)max(cnt[t], 1));
}

// single-workgroup exclusive scan, n <= ~1M
__global__ __launch_bounds__(1024) void exscan_k(const int* __restrict__ cnt,
                                                 int* __restrict__ off, int n) {
  __shared__ int ts[1024];
  const int t = threadIdx.x;
  const int per = (n + 1023) >> 10;
  const int b = min(t * per, n);
  const int e = min(b + per, n);
  int s = 0;
  for (int i = b; i < e; ++i) s += cnt[i];
  ts[t] = s;
  __syncthreads();
  for (int d = 1; d < 1024; d <<= 1) {
    int v = (t >= d) ? ts[t - d] : 0;
    __syncthreads();
    ts[t] += v;
    __syncthreads();
  }
  if (t == 1023) off[n] = ts[1023];
  int run = (t == 0) ? 0 : ts[t - 1];
  for (int i = b; i < e; ++i) { off[i] = run; run += cnt[i]; }
}

__global__ void copyi_k(int* __restrict__ dst, const int* __restrict__ src, int n) {
  int t = blockIdx.x * 256 + threadIdx.x;
  if (t < n) dst[t] = src[t];
}

// CSR fill, src index only (weight looked up at gather time)
__global__ void fill_k(const int* __restrict__ dstA, const int* __restrict__ srcA,
                       int* __restrict__ cur, int* __restrict__ csrc, int E) {
  int e = blockIdx.x * 256 + threadIdx.x;
  if (e >= E) return;
  int pos = atomicAdd(&cur[dstA[e]], 1);
  csrc[pos] = srcA[e];
}

// CSR fill with folded per-edge weight (UG user side): w = invS[src]*wn[src]*we[e]
__global__ void fill_w_k(const int* __restrict__ dstA, const int* __restrict__ srcA,
                         const float* __restrict__ invS, const float* __restrict__ wn,
                         const float* __restrict__ we,
                         int* __restrict__ cur, int* __restrict__ csrc,
                         float* __restrict__ cwt, int E) {
  int e = blockIdx.x * 256 + threadIdx.x;
  if (e >= E) return;
  int dn = dstA[e], sn = srcA[e];
  int pos = atomicAdd(&cur[dn], 1);
  csrc[pos] = sn;
  cwt[pos] = invS[sn] * wn[sn] * we[e];
}

// ---------- pull aggregation: one 64-lane wave per dst row ----------
__global__ __launch_bounds__(256) void gather_k(const float* __restrict__ x,
    const int* __restrict__ roff, const int* __restrict__ csrc,
    const float* __restrict__ cwt, const float* __restrict__ invS,
    const float* __restrict__ invD, float* __restrict__ out, int nrows) {
  int wid = (blockIdx.x << 2) | (threadIdx.x >> 6);
  if (wid >= nrows) return;
  int lane = threadIdx.x & 63;
  int beg = __builtin_amdgcn_readfirstlane(roff[wid]);
  int end = __builtin_amdgcn_readfirstlane(roff[wid + 1]);
  const float2* __restrict__ x2 = (const float2*)x;
  float ax = 0.f, ay = 0.f;
  for (int j = beg; j < end; ++j) {
    int s = csrc[j];
    float w = cwt ? cwt[j] : invS[s];
    float2 v = x2[(size_t)s * 64 + lane];
    ax = fmaf(w, v.x, ax);
    ay = fmaf(w, v.y, ay);
  }
  float si = invD[wid];
  float2 o;
  o.x = ax * si;
  o.y = ay * si;
  ((float2*)out)[(size_t)wid * 64 + lane] = o;
}

// ---------- layer attention (unchanged from round 0, verified) ----------

__device__ inline void osm_upd(float& m, float& den, float& num, float sc, float tv) {
  float nm = fmaxf(m, sc);
  float e0 = __expf(m - nm);
  float e1 = __expf(sc - nm);
  den = den * e0 + e1;
  num = num * e0 + tv * e1;
  m = nm;
}

template <int L>
__global__ __launch_bounds__(256) void attn_k(AttnArgs args,
    const float* __restrict__ W, const float* __restrict__ avec,
    float* __restrict__ out, float out_scale, int beta, int n) {
  __shared__ float xs[8][D];
  const int nt = threadIdx.x >> 5;
  const int dt = threadIdx.x & 31;
  const float4 a4 = ((const float4*)avec)[dt];
  const float4* __restrict__ W4 = (const float4*)W;

  int node = blockIdx.x * 8 + nt;
  float m[4], den[4], num[4];
#pragma unroll
  for (int j = 0; j < 4; ++j) { m[j] = -3.0e38f; den[j] = 0.f; num[j] = 0.f; }

#pragma unroll
  for (int l = 0; l < L; ++l) {
    __syncthreads();
    if (node < n)
      ((float4*)xs[nt])[dt] = ((const float4*)(args.layer[l] + (size_t)node * D))[dt];
    __syncthreads();
    if (node < n) {
      float s0 = 0.f, s1 = 0.f, s2 = 0.f, s3 = 0.f;
#pragma unroll 8
      for (int k = 0; k < D; ++k) {
        float xv = xs[nt][k];
        float4 w = W4[k * 32 + dt];
        s0 = fmaf(xv, w.x, s0);
        s1 = fmaf(xv, w.y, s1);
        s2 = fmaf(xv, w.z, s2);
        s3 = fmaf(xv, w.w, s3);
      }
      float c = args.coef[l];
      float4 tv = ((float4*)xs[nt])[dt];
      osm_upd(m[0], den[0], num[0], c * s0 * a4.x, c * tv.x);
      osm_upd(m[1], den[1], num[1], c * s1 * a4.y, c * tv.y);
      osm_upd(m[2], den[2], num[2], c * s2 * a4.z, c * tv.z);
      osm_upd(m[3], den[3], num[3], c * s3 * a4.w, c * tv.w);
    }
  }
  if (node < n) {
    float4 o;
    o.x = num[0] / den[0];
    o.y = num[1] / den[1];
    o.z = num[2] / den[2];
    o.w = num[3] / den[3];
    float4* op = ((float4*)(out + (size_t)node * D)) + dt;
    if (beta) {
      float4 pv = *op;
      o.x = pv.x + out_scale * o.x;
      o.y = pv.y + out_scale * o.y;
      o.z = pv.z + out_scale * o.z;
      o.w = pv.w + out_scale * o.w;
    } else {
      o.x *= out_scale; o.y *= out_scale; o.z *= out_scale; o.w *= out_scale;
    }
    *op = o;
  }
}

__global__ void axpy4_k(float* __restrict__ dst, const float* __restrict__ src, float a, long n4) {
  long t = (long)blockIdx.x * 256 + threadIdx.x;
  if (t < n4) {
    float4 v = ((const float4*)src)[t];
    float4 o = ((float4*)dst)[t];
    o.x += a * v.x; o.y += a * v.y; o.z += a * v.z; o.w += a * v.w;
    ((float4*)dst)[t] = o;
  }
}

inline dim3 g1(long n) { return dim3((unsigned)((n + 255) / 256)); }
inline dim3 gw(int rows) { return dim3((unsigned)((rows + 3) / 4)); }  // 4 waves/block

} // namespace

extern "C" void kernel_launch(void* const* d_in, const int* in_sizes, int n_in,
                              void* d_out, int out_size, void* d_ws, size_t ws_size,
                              hipStream_t stream) {
  const int* ug_u = (const int*)d_in[0];
  const int* ug_g = (const int*)d_in[1];
  const int* aS[3] = {(const int*)d_in[2], (const int*)d_in[4], (const int*)d_in[6]};
  const int* aD[3] = {(const int*)d_in[3], (const int*)d_in[5], (const int*)d_in[7]};
  const int* oS = (const int*)d_in[8];
  const int* oD = (const int*)d_in[9];
  const float* ue    = (const float*)d_in[10];
  const float* ie    = (const float*)d_in[11];
  const float* W_and = (const float*)d_in[12];
  const float* a_and = (const float*)d_in[13];
  const float* W_or  = (const float*)d_in[14];
  const float* a_or  = (const float*)d_in[15];
  const float* wedge = (const float*)d_in[16];
  const float* wnode = (const float*)d_in[17];

  // ---- workspace carve-up (16B-aligned bumps) ----
  char* base = (char*)d_ws;
  size_t boff = 0;
  auto alloc = [&](size_t bytes) -> void* {
    void* r = base + boff;
    boff += (bytes + 15) & ~(size_t)15;
    return r;
  };

  const int NCNT = NU + 9 * NI;
  int* cnt_all = (int*)alloc((size_t)NCNT * 4);   // contiguous: cU,cG,cAs/cAd x3,cOs,cOd
  float* inv_all = (float*)alloc((size_t)NCNT * 4);
  int* cU  = cnt_all;
  int* cG  = cU + NU;
  int* cAs[3], *cAd[3];
  { int* p = cG + NI;
    for (int i = 0; i < 3; ++i) { cAs[i] = p; p += NI; cAd[i] = p; p += NI; }
  }
  int* cOs = cAd[2] + NI;
  int* cOd = cOs + NI;
  float* invU = inv_all;
  float* invG = invU + NU;
  float* iAo[3], *iAi[3];
  { float* p = invG + NI;
    for (int i = 0; i < 3; ++i) { iAo[i] = p; p += NI; iAi[i] = p; p += NI; }
  }
  float* iOo = iAi[2] + NI;
  float* iOi = iOo + NI;

  const int NOFF = (NU + 1) + 5 * (NI + 1);
  int* off_all = (int*)alloc((size_t)NOFF * 4);
  int* cur_all = (int*)alloc((size_t)NOFF * 4);
  int* oUGu = off_all;                 // by dst=u, counts cU
  int* oUGg = oUGu + (NU + 1);         // by dst=g, counts cG
  int* oAnd[3] = {oUGg + (NI + 1), oUGg + 2 * (NI + 1), oUGg + 3 * (NI + 1)};
  int* oOr  = oUGg + 4 * (NI + 1);
  int* curUGu = cur_all;
  int* curUGg = curUGu + (NU + 1);
  int* curAnd[3] = {curUGg + (NI + 1), curUGg + 2 * (NI + 1), curUGg + 3 * (NI + 1)};
  int* curOr  = curUGg + 4 * (NI + 1);

  int* sUGu = (int*)alloc((size_t)EUG * 4);
  float* wUGu = (float*)alloc((size_t)EUG * 4);
  int* sUGg = (int*)alloc((size_t)EUG * 4);
  int* sAnd[3];
  for (int i = 0; i < 3; ++i) sAnd[i] = (int*)alloc((size_t)EAND * 4);
  int* sOr = (int*)alloc((size_t)EOR * 4);

  float* hu1 = (float*)alloc((size_t)NU * D * 4);
  float* hg1 = (float*)alloc((size_t)NI * D * 4);
  float* hg2 = (float*)alloc((size_t)NI * D * 4);
  float* ab[6]; for (int i = 0; i < 6; ++i) ab[i] = (float*)alloc((size_t)NI * D * 4);
  float* ob[3]; for (int i = 0; i < 3; ++i) ob[i] = (float*)alloc((size_t)NI * D * 4);

  float* out_hu = (float*)d_out;
  float* out_game = out_hu + (size_t)NU * D;

  // ---- degrees ----
  hipMemsetAsync(cnt_all, 0, (size_t)NCNT * 4, stream);
  count_k<<<g1(EUG), 256, 0, stream>>>(ug_u, EUG, cU);
  count_k<<<g1(EUG), 256, 0, stream>>>(ug_g, EUG, cG);
  for (int i = 0; i < 3; ++i) {
    count_k<<<g1(EAND), 256, 0, stream>>>(aS[i], EAND, cAs[i]);
    count_k<<<g1(EAND), 256, 0, stream>>>(aD[i], EAND, cAd[i]);
  }
  count_k<<<g1(EOR), 256, 0, stream>>>(oS, EOR, cOs);
  count_k<<<g1(EOR), 256, 0, stream>>>(oD, EOR, cOd);
  norms_k<<<g1(NCNT), 256, 0, stream>>>(cnt_all, inv_all, NCNT);

  // ---- CSR offsets ----
  exscan_k<<<1, 1024, 0, stream>>>(cU, oUGu, NU);
  exscan_k<<<1, 1024, 0, stream>>>(cG, oUGg, NI);
  for (int i = 0; i < 3; ++i) exscan_k<<<1, 1024, 0, stream>>>(cAd[i], oAnd[i], NI);
  exscan_k<<<1, 1024, 0, stream>>>(cOd, oOr, NI);
  copyi_k<<<g1(NOFF), 256, 0, stream>>>(cur_all, off_all, NOFF);

  // ---- CSR fill ----
  fill_w_k<<<g1(EUG), 256, 0, stream>>>(ug_u, ug_g, invG, wnode, wedge, curUGu, sUGu, wUGu, EUG);
  fill_k<<<g1(EUG), 256, 0, stream>>>(ug_g, ug_u, curUGg, sUGg, EUG);
  for (int i = 0; i < 3; ++i)
    fill_k<<<g1(EAND), 256, 0, stream>>>(aD[i], aS[i], curAnd[i], sAnd[i], EAND);
  fill_k<<<g1(EOR), 256, 0, stream>>>(oD, oS, curOr, sOr, EOR);

  // ---- UG propagation (2 layers); hu2 goes straight to d_out ----
  gather_k<<<gw(NU), 256, 0, stream>>>(ie,  oUGu, sUGu, wUGu, nullptr, invU, hu1, NU);
  gather_k<<<gw(NI), 256, 0, stream>>>(ue,  oUGg, sUGg, nullptr, invU, invG, hg1, NI);
  gather_k<<<gw(NU), 256, 0, stream>>>(hg1, oUGu, sUGu, wUGu, nullptr, invU, out_hu, NU);
  gather_k<<<gw(NI), 256, 0, stream>>>(hu1, oUGg, sUGg, nullptr, invU, invG, hg2, NI);

  // ---- AND chains: 3 graphs x 2 layers ----
  for (int i = 0; i < 3; ++i)
    gather_k<<<gw(NI), 256, 0, stream>>>(ie, oAnd[i], sAnd[i], nullptr, iAo[i], iAi[i], ab[i], NI);
  for (int i = 0; i < 3; ++i)
    gather_k<<<gw(NI), 256, 0, stream>>>(ab[i], oAnd[i], sAnd[i], nullptr, iAo[i], iAi[i], ab[3 + i], NI);

  // ---- OR chain: 3 layers ----
  gather_k<<<gw(NI), 256, 0, stream>>>(ie,    oOr, sOr, nullptr, iOo, iOi, ob[0], NI);
  gather_k<<<gw(NI), 256, 0, stream>>>(ob[0], oOr, sOr, nullptr, iOo, iOi, ob[1], NI);
  gather_k<<<gw(NI), 256, 0, stream>>>(ob[1], oOr, sOr, nullptr, iOo, iOi, ob[2], NI);

  const float w_or = 80.0f / 82.0f;
  const float w_and = w_or / 80.0f;   // = 1/82
  const float w_self = w_and;

  // ---- layer attention ----
  AttnArgs aa{};
  aa.layer[0] = ie;
  for (int i = 0; i < 6; ++i) aa.layer[1 + i] = ab[i];
  for (int i = 0; i < 7; ++i) aa.coef[i] = 1.0f;
  attn_k<7><<<dim3((NI + 7) / 8), 256, 0, stream>>>(aa, W_and, a_and, out_game, w_and, 0, NI);

  AttnArgs ao{};
  ao.layer[0] = ie; ao.layer[1] = ob[0]; ao.layer[2] = ob[1]; ao.layer[3] = ob[2];
  ao.coef[0] = 1.0f; ao.coef[1] = 0.6f; ao.coef[2] = 0.8f; ao.coef[3] = 1.0f;
  attn_k<4><<<dim3((NI + 7) / 8), 256, 0, stream>>>(ao, W_or, a_or, out_game, w_or, 1, NI);

  // ---- combine: out_game += w_self * hg2 ----
  axpy4_k<<<g1((long)NI * 32), 256, 0, stream>>>(out_game, hg2, w_self, (long)NI * 32);
}

// Round 3
// 2538.203 us; speedup vs baseline: 11.7359x; 1.2627x over previous
//
#include <hip/hip_runtime.h>
#include <hip/hip_bf16.h>
#include <math.h>

namespace {

constexpr int NU   = 50000;
constexpr int NI   = 30000;
constexpr int D    = 128;
constexpr int EUG  = 2000000;
constexpr int EAND = 1000000;
constexpr int EOR  = 1000000;

// ---------- fused degree counts ----------
struct CountAll {
  const int* idx[10];
  int* cnt[10];
  int n[10];
  int blkbase[11];
};
__global__ __launch_bounds__(256) void count_all_k(CountAll C) {
  int seg = 0;
#pragma unroll
  for (int i = 1; i < 10; ++i) if ((int)blockIdx.x >= C.blkbase[i]) seg = i;
  int t = ((int)blockIdx.x - C.blkbase[seg]) * 256 + (int)threadIdx.x;
  if (t < C.n[seg]) atomicAdd(&C.cnt[seg][C.idx[seg][t]], 1);
}

__global__ void norms_k(const int* __restrict__ cnt, float* __restrict__ inv, int n) {
  int t = blockIdx.x * 256 + threadIdx.x;
  if (t < n) inv[t] = rsqrtf((float)max(cnt[t], 1));
}

// ---------- fused exclusive scans (one workgroup per segment) ----------
struct ScanSeg { const int* cnt; int* off; int* cur; int n; };
struct ScanAll { ScanSeg s[6]; };
__global__ __launch_bounds__(1024) void exscan_multi_k(ScanAll S) {
  ScanSeg sg = S.s[blockIdx.x];
  __shared__ int ts[1024];
  const int t = threadIdx.x;
  const int per = (sg.n + 1023) >> 10;
  const int b = min(t * per, sg.n);
  const int e = min(b + per, sg.n);
  int s = 0;
  for (int i = b; i < e; ++i) s += sg.cnt[i];
  ts[t] = s;
  __syncthreads();
  for (int d = 1; d < 1024; d <<= 1) {
    int v = (t >= d) ? ts[t - d] : 0;
    __syncthreads();
    ts[t] += v;
    __syncthreads();
  }
  if (t == 1023) sg.off[sg.n] = ts[1023];
  int run = (t == 0) ? 0 : ts[t - 1];
  for (int i = b; i < e; ++i) { sg.off[i] = run; sg.cur[i] = run; run += sg.cnt[i]; }
}

// ---------- fused CSR fills ----------
struct FillAll {
  const int* dst[6];
  const int* src[6];
  int* cur[6];
  int* csrc[6];
  float* cwt;           // segment 0 only (UG user side)
  const float* invS0;   // invG
  const float* wn0;
  const float* we0;
  int n[6];
  int blkbase[7];
};
__global__ __launch_bounds__(256) void fill_all_k(FillAll F) {
  int seg = 0;
#pragma unroll
  for (int i = 1; i < 6; ++i) if ((int)blockIdx.x >= F.blkbase[i]) seg = i;
  int e = ((int)blockIdx.x - F.blkbase[seg]) * 256 + (int)threadIdx.x;
  if (e >= F.n[seg]) return;
  int dn = F.dst[seg][e], sn = F.src[seg][e];
  int pos = atomicAdd(&F.cur[seg][dn], 1);
  F.csrc[seg][pos] = sn;
  if (seg == 0) F.cwt[pos] = F.invS0[sn] * F.wn0[sn] * F.we0[e];
}

// ---------- multi-job pull aggregation: one 64-lane wave per dst row ----------
struct GJob {
  const float* x; const int* roff; const int* csrc; const float* cwt;
  const float* invS; const float* invD; float* out; int rbeg;
};
struct GJobs { GJob j[3]; int total; };

__global__ __launch_bounds__(256) void gather_multi_k(GJobs J) {
  int wid = ((int)blockIdx.x << 2) | ((int)threadIdx.x >> 6);
  if (wid >= J.total) return;
  GJob jb = J.j[0];
  if (wid >= J.j[1].rbeg) jb = J.j[1];
  if (wid >= J.j[2].rbeg) jb = J.j[2];
  int row = wid - jb.rbeg;
  int lane = (int)threadIdx.x & 63;
  int beg = __builtin_amdgcn_readfirstlane(jb.roff[row]);
  int end = __builtin_amdgcn_readfirstlane(jb.roff[row + 1]);
  const float2* __restrict__ x2 = (const float2*)jb.x;
  const int* __restrict__ cs = jb.csrc;
  float ax = 0.f, ay = 0.f;
  int j = beg;
  if (jb.cwt) {
    const float* __restrict__ cw = jb.cwt;
    for (; j + 3 < end; j += 4) {
      int s0 = cs[j], s1 = cs[j+1], s2 = cs[j+2], s3 = cs[j+3];
      float w0 = cw[j], w1 = cw[j+1], w2 = cw[j+2], w3 = cw[j+3];
      float2 v0 = x2[(size_t)s0 * 64 + lane];
      float2 v1 = x2[(size_t)s1 * 64 + lane];
      float2 v2 = x2[(size_t)s2 * 64 + lane];
      float2 v3 = x2[(size_t)s3 * 64 + lane];
      ax = fmaf(w0, v0.x, ax); ay = fmaf(w0, v0.y, ay);
      ax = fmaf(w1, v1.x, ax); ay = fmaf(w1, v1.y, ay);
      ax = fmaf(w2, v2.x, ax); ay = fmaf(w2, v2.y, ay);
      ax = fmaf(w3, v3.x, ax); ay = fmaf(w3, v3.y, ay);
    }
    for (; j < end; ++j) {
      int s = cs[j]; float w = cw[j];
      float2 v = x2[(size_t)s * 64 + lane];
      ax = fmaf(w, v.x, ax); ay = fmaf(w, v.y, ay);
    }
  } else {
    const float* __restrict__ is = jb.invS;
    for (; j + 3 < end; j += 4) {
      int s0 = cs[j], s1 = cs[j+1], s2 = cs[j+2], s3 = cs[j+3];
      float w0 = is[s0], w1 = is[s1], w2 = is[s2], w3 = is[s3];
      float2 v0 = x2[(size_t)s0 * 64 + lane];
      float2 v1 = x2[(size_t)s1 * 64 + lane];
      float2 v2 = x2[(size_t)s2 * 64 + lane];
      float2 v3 = x2[(size_t)s3 * 64 + lane];
      ax = fmaf(w0, v0.x, ax); ay = fmaf(w0, v0.y, ay);
      ax = fmaf(w1, v1.x, ax); ay = fmaf(w1, v1.y, ay);
      ax = fmaf(w2, v2.x, ax); ay = fmaf(w2, v2.y, ay);
      ax = fmaf(w3, v3.x, ax); ay = fmaf(w3, v3.y, ay);
    }
    for (; j < end; ++j) {
      int s = cs[j]; float w = is[s];
      float2 v = x2[(size_t)s * 64 + lane];
      ax = fmaf(w, v.x, ax); ay = fmaf(w, v.y, ay);
    }
  }
  float si = jb.invD[row];
  float2 o; o.x = ax * si; o.y = ay * si;
  ((float2*)jb.out)[(size_t)row * 64 + lane] = o;
}

// ---------- layer attention: W-half + x rows in LDS, channel-split grid ----------
struct AttnArgs {
  const float* layer[7];
  float coef[7];
};

__device__ inline void osm_upd(float& m, float& den, float& num, float sc, float tv) {
  float nm = fmaxf(m, sc);
  float e0 = __expf(m - nm);
  float e1 = __expf(sc - nm);
  den = den * e0 + e1;
  num = num * e0 + tv * e1;
  m = nm;
}

// block: 256 threads = 16 dt (x float4 = 64 channels) x 16 groups; each group
// handles rows grp and grp+16 -> 32 nodes/block. blockIdx.y = channel half.
template <int L>
__global__ __launch_bounds__(256) void attn_k(AttnArgs args,
    const float* __restrict__ W, const float* __restrict__ avec,
    float* __restrict__ out, float out_scale, int beta,
    const float* __restrict__ extra, float escale, int n) {
  __shared__ float4 Ws4[2048];     // [k=128][dt=16] of this half: 32 KB
  __shared__ float xs[32][132];    // 32 node rows, +4 pad to break bank aliasing
  const int tid = threadIdx.x;
  const int dt = tid & 15;
  const int grp = tid >> 4;
  const int half = blockIdx.y;
  const int base = blockIdx.x * 32;
  const float4* __restrict__ W4 = (const float4*)W;

  for (int i = tid; i < 2048; i += 256) {
    int k = i >> 4, d = i & 15;
    Ws4[i] = W4[(k << 5) + (half << 4) + d];
  }
  const float4 a4 = ((const float4*)avec)[(half << 4) + dt];
  const float am[4] = {a4.x, a4.y, a4.z, a4.w};

  float m[2][4], den[2][4], num[2][4];
#pragma unroll
  for (int g = 0; g < 2; ++g)
#pragma unroll
    for (int c = 0; c < 4; ++c) { m[g][c] = -3.0e38f; den[g][c] = 0.f; num[g][c] = 0.f; }

#pragma unroll
  for (int l = 0; l < L; ++l) {
    __syncthreads();
    const float4* __restrict__ L4 = (const float4*)args.layer[l];
    for (int i = tid; i < 1024; i += 256) {
      int r = i >> 5, c4 = i & 31;
      int node = base + r;
      float4 v = (node < n) ? L4[(size_t)node * 32 + c4] : make_float4(0.f, 0.f, 0.f, 0.f);
      *(float4*)&xs[r][c4 << 2] = v;
    }
    __syncthreads();
    float s0[4] = {0.f, 0.f, 0.f, 0.f}, s1[4] = {0.f, 0.f, 0.f, 0.f};
#pragma unroll 4
    for (int k = 0; k < 128; ++k) {
      float4 w = Ws4[(k << 4) + dt];
      float x0 = xs[grp][k];
      float x1 = xs[grp + 16][k];
      s0[0] = fmaf(x0, w.x, s0[0]); s0[1] = fmaf(x0, w.y, s0[1]);
      s0[2] = fmaf(x0, w.z, s0[2]); s0[3] = fmaf(x0, w.w, s0[3]);
      s1[0] = fmaf(x1, w.x, s1[0]); s1[1] = fmaf(x1, w.y, s1[1]);
      s1[2] = fmaf(x1, w.z, s1[2]); s1[3] = fmaf(x1, w.w, s1[3]);
    }
    float c = args.coef[l];
    float4 t0 = *(const float4*)&xs[grp][(half << 6) + (dt << 2)];
    float4 t1 = *(const float4*)&xs[grp + 16][(half << 6) + (dt << 2)];
    const float tv0[4] = {t0.x, t0.y, t0.z, t0.w};
    const float tv1[4] = {t1.x, t1.y, t1.z, t1.w};
#pragma unroll
    for (int ch = 0; ch < 4; ++ch) {
      osm_upd(m[0][ch], den[0][ch], num[0][ch], c * s0[ch] * am[ch], c * tv0[ch]);
      osm_upd(m[1][ch], den[1][ch], num[1][ch], c * s1[ch] * am[ch], c * tv1[ch]);
    }
  }
#pragma unroll
  for (int g = 0; g < 2; ++g) {
    int node = base + grp + g * 16;
    if (node >= n) continue;
    float4 o;
    o.x = num[g][0] / den[g][0];
    o.y = num[g][1] / den[g][1];
    o.z = num[g][2] / den[g][2];
    o.w = num[g][3] / den[g][3];
    size_t oi = (size_t)node * 32 + (half << 4) + dt;
    float4* op = (float4*)out + oi;
    if (beta) {
      float4 pv = *op;
      float4 ev = extra ? ((const float4*)extra)[oi] : make_float4(0.f, 0.f, 0.f, 0.f);
      o.x = pv.x + out_scale * o.x + escale * ev.x;
      o.y = pv.y + out_scale * o.y + escale * ev.y;
      o.z = pv.z + out_scale * o.z + escale * ev.z;
      o.w = pv.w + out_scale * o.w + escale * ev.w;
    } else {
      o.x *= out_scale; o.y *= out_scale; o.z *= out_scale; o.w *= out_scale;
    }
    *op = o;
  }
}

inline dim3 g1(long n) { return dim3((unsigned)((n + 255) / 256)); }

} // namespace

extern "C" void kernel_launch(void* const* d_in, const int* in_sizes, int n_in,
                              void* d_out, int out_size, void* d_ws, size_t ws_size,
                              hipStream_t stream) {
  const int* ug_u = (const int*)d_in[0];
  const int* ug_g = (const int*)d_in[1];
  const int* aS[3] = {(const int*)d_in[2], (const int*)d_in[4], (const int*)d_in[6]};
  const int* aD[3] = {(const int*)d_in[3], (const int*)d_in[5], (const int*)d_in[7]};
  const int* oS = (const int*)d_in[8];
  const int* oD = (const int*)d_in[9];
  const float* ue    = (const float*)d_in[10];
  const float* ie    = (const float*)d_in[11];
  const float* W_and = (const float*)d_in[12];
  const float* a_and = (const float*)d_in[13];
  const float* W_or  = (const float*)d_in[14];
  const float* a_or  = (const float*)d_in[15];
  const float* wedge = (const float*)d_in[16];
  const float* wnode = (const float*)d_in[17];

  // ---- workspace carve-up ----
  char* basep = (char*)d_ws;
  size_t boff = 0;
  auto alloc = [&](size_t bytes) -> void* {
    void* r = basep + boff;
    boff += (bytes + 15) & ~(size_t)15;
    return r;
  };

  const int NCNT = NU + 9 * NI;
  int* cnt_all = (int*)alloc((size_t)NCNT * 4);
  float* inv_all = (float*)alloc((size_t)NCNT * 4);
  int* cU = cnt_all;
  int* cG = cU + NU;
  int* cAs[3], *cAd[3];
  { int* p = cG + NI;
    for (int i = 0; i < 3; ++i) { cAs[i] = p; p += NI; cAd[i] = p; p += NI; } }
  int* cOs = cAd[2] + NI;
  int* cOd = cOs + NI;
  float* invU = inv_all;
  float* invG = invU + NU;
  float* iAo[3], *iAi[3];
  { float* p = invG + NI;
    for (int i = 0; i < 3; ++i) { iAo[i] = p; p += NI; iAi[i] = p; p += NI; } }
  float* iOo = iAi[2] + NI;
  float* iOi = iOo + NI;

  int* oUGu = (int*)alloc((size_t)(NU + 1) * 4);
  int* oUGg = (int*)alloc((size_t)(NI + 1) * 4);
  int* oAnd[3]; for (int i = 0; i < 3; ++i) oAnd[i] = (int*)alloc((size_t)(NI + 1) * 4);
  int* oOr = (int*)alloc((size_t)(NI + 1) * 4);
  int* curUGu = (int*)alloc((size_t)(NU + 1) * 4);
  int* curUGg = (int*)alloc((size_t)(NI + 1) * 4);
  int* curAnd[3]; for (int i = 0; i < 3; ++i) curAnd[i] = (int*)alloc((size_t)(NI + 1) * 4);
  int* curOr = (int*)alloc((size_t)(NI + 1) * 4);

  int* sUGu = (int*)alloc((size_t)EUG * 4);
  float* wUGu = (float*)alloc((size_t)EUG * 4);
  int* sUGg = (int*)alloc((size_t)EUG * 4);
  int* sAnd[3]; for (int i = 0; i < 3; ++i) sAnd[i] = (int*)alloc((size_t)EAND * 4);
  int* sOr = (int*)alloc((size_t)EOR * 4);

  float* hu1 = (float*)alloc((size_t)NU * D * 4);
  float* hg1 = (float*)alloc((size_t)NI * D * 4);
  float* hg2 = (float*)alloc((size_t)NI * D * 4);
  float* ab[6]; for (int i = 0; i < 6; ++i) ab[i] = (float*)alloc((size_t)NI * D * 4);
  float* ob[3]; for (int i = 0; i < 3; ++i) ob[i] = (float*)alloc((size_t)NI * D * 4);

  float* out_hu = (float*)d_out;
  float* out_game = out_hu + (size_t)NU * D;

  // ---- degrees (fused) ----
  hipMemsetAsync(cnt_all, 0, (size_t)NCNT * 4, stream);
  CountAll C{};
  {
    const int* idxs[10] = {ug_u, ug_g, aS[0], aD[0], aS[1], aD[1], aS[2], aD[2], oS, oD};
    int* cnts[10] = {cU, cG, cAs[0], cAd[0], cAs[1], cAd[1], cAs[2], cAd[2], cOs, cOd};
    int ns[10] = {EUG, EUG, EAND, EAND, EAND, EAND, EAND, EAND, EOR, EOR};
    int bb = 0;
    for (int i = 0; i < 10; ++i) {
      C.idx[i] = idxs[i]; C.cnt[i] = cnts[i]; C.n[i] = ns[i];
      C.blkbase[i] = bb; bb += (ns[i] + 255) / 256;
    }
    C.blkbase[10] = bb;
  }
  count_all_k<<<dim3(C.blkbase[10]), 256, 0, stream>>>(C);
  norms_k<<<g1(NCNT), 256, 0, stream>>>(cnt_all, inv_all, NCNT);

  // ---- scans (fused, writes off + cur) ----
  ScanAll SA{};
  SA.s[0] = {cU, oUGu, curUGu, NU};
  SA.s[1] = {cG, oUGg, curUGg, NI};
  for (int i = 0; i < 3; ++i) SA.s[2 + i] = {cAd[i], oAnd[i], curAnd[i], NI};
  SA.s[5] = {cOd, oOr, curOr, NI};
  exscan_multi_k<<<dim3(6), 1024, 0, stream>>>(SA);

  // ---- CSR fills (fused) ----
  FillAll F{};
  {
    const int* ds[6] = {ug_u, ug_g, aD[0], aD[1], aD[2], oD};
    const int* ss[6] = {ug_g, ug_u, aS[0], aS[1], aS[2], oS};
    int* cs[6] = {curUGu, curUGg, curAnd[0], curAnd[1], curAnd[2], curOr};
    int* os[6] = {sUGu, sUGg, sAnd[0], sAnd[1], sAnd[2], sOr};
    int ns[6] = {EUG, EUG, EAND, EAND, EAND, EOR};
    int bb = 0;
    for (int i = 0; i < 6; ++i) {
      F.dst[i] = ds[i]; F.src[i] = ss[i]; F.cur[i] = cs[i]; F.csrc[i] = os[i]; F.n[i] = ns[i];
      F.blkbase[i] = bb; bb += (ns[i] + 255) / 256;
    }
    F.blkbase[6] = bb;
    F.cwt = wUGu; F.invS0 = invG; F.wn0 = wnode; F.we0 = wedge;
  }
  fill_all_k<<<dim3(F.blkbase[6]), 256, 0, stream>>>(F);

  // ---- gathers (multi-job) ----
  auto launch_gather = [&](GJob a, GJob b, GJob c, int nj, int r0, int r1, int r2) {
    GJobs J{};
    int tot = r0 + (nj > 1 ? r1 : 0) + (nj > 2 ? r2 : 0);
    a.rbeg = 0;
    b.rbeg = (nj > 1) ? r0 : tot;
    c.rbeg = (nj > 2) ? r0 + r1 : tot;
    J.j[0] = a;
    J.j[1] = (nj > 1) ? b : a; if (nj <= 1) J.j[1].rbeg = tot;
    J.j[2] = (nj > 2) ? c : a; if (nj <= 2) J.j[2].rbeg = tot;
    J.total = tot;
    gather_multi_k<<<dim3((tot + 3) / 4), 256, 0, stream>>>(J);
  };
  GJob z{};  // filler

  // UG layer 1: hu1 <- ie (weighted CSR), hg1 <- ue
  launch_gather({ie, oUGu, sUGu, wUGu, nullptr, invU, hu1, 0},
                {ue, oUGg, sUGg, nullptr, invU, invG, hg1, 0}, z, 2, NU, NI, 0);
  // UG layer 2: out_hu <- hg1, hg2 <- hu1
  launch_gather({hg1, oUGu, sUGu, wUGu, nullptr, invU, out_hu, 0},
                {hu1, oUGg, sUGg, nullptr, invU, invG, hg2, 0}, z, 2, NU, NI, 0);
  // AND layer 1 (3 independent graphs)
  launch_gather({ie, oAnd[0], sAnd[0], nullptr, iAo[0], iAi[0], ab[0], 0},
                {ie, oAnd[1], sAnd[1], nullptr, iAo[1], iAi[1], ab[1], 0},
                {ie, oAnd[2], sAnd[2], nullptr, iAo[2], iAi[2], ab[2], 0}, 3, NI, NI, NI);
  // AND layer 2
  launch_gather({ab[0], oAnd[0], sAnd[0], nullptr, iAo[0], iAi[0], ab[3], 0},
                {ab[1], oAnd[1], sAnd[1], nullptr, iAo[1], iAi[1], ab[4], 0},
                {ab[2], oAnd[2], sAnd[2], nullptr, iAo[2], iAi[2], ab[5], 0}, 3, NI, NI, NI);
  // OR chain (serial)
  launch_gather({ie,    oOr, sOr, nullptr, iOo, iOi, ob[0], 0}, z, z, 1, NI, 0, 0);
  launch_gather({ob[0], oOr, sOr, nullptr, iOo, iOi, ob[1], 0}, z, z, 1, NI, 0, 0);
  launch_gather({ob[1], oOr, sOr, nullptr, iOo, iOi, ob[2], 0}, z, z, 1, NI, 0, 0);

  const float w_or = 80.0f / 82.0f;
  const float w_and = w_or / 80.0f;   // = 1/82
  const float w_self = w_and;

  // ---- layer attention ----
  AttnArgs aa{};
  aa.layer[0] = ie;
  for (int i = 0; i < 6; ++i) aa.layer[1 + i] = ab[i];
  for (int i = 0; i < 7; ++i) aa.coef[i] = 1.0f;
  attn_k<7><<<dim3((NI + 31) / 32, 2), 256, 0, stream>>>(
      aa, W_and, a_and, out_game, w_and, 0, nullptr, 0.f, NI);

  AttnArgs ao{};
  ao.layer[0] = ie; ao.layer[1] = ob[0]; ao.layer[2] = ob[1]; ao.layer[3] = ob[2];
  ao.coef[0] = 1.0f; ao.coef[1] = 0.6f; ao.coef[2] = 0.8f; ao.coef[3] = 1.0f;
  attn_k<4><<<dim3((NI + 31) / 32, 2), 256, 0, stream>>>(
      ao, W_or, a_or, out_game, w_or, 1, hg2, w_self, NI);
}